// Round 6
// baseline (475.234 us; speedup 1.0000x reference)
//
#include <hip/hip_runtime.h>

#define NQ 8
#define KCODES 1024
#define D 64
#define CHUNK 64             // prep_cb granule (64-code chunks, ws_cb layout unchanged)
#define TPB 256
#define TOKPB 32             // tokens per block = 2 groups x 16  (R6: halved -> 8 blocks/CU)
#define BIAS 96.0f

using short8 = __attribute__((ext_vector_type(8))) short;
using f32x4  = __attribute__((ext_vector_type(4))) float;

static __device__ __forceinline__ unsigned bf16_rne_bits(float f) {
    unsigned u = __float_as_uint(f);
    return (u + 0x7fffu + ((u >> 16) & 1u)) >> 16;   // bf16 RNE bit pattern
}
static __device__ __forceinline__ unsigned umn(unsigned a, unsigned b) { return a < b ? a : b; }
static __device__ __forceinline__ unsigned umx(unsigned a, unsigned b) { return a > b ? a : b; }
// true 3-input median in one VOP3 (no clang builtin for u32 med3 -> inline asm).
// NOTE: inputs must NOT be direct MFMA outputs (hazard cover) — keep >=1 plain VALU op
// between an MFMA result and any inline-asm consumer (R3/R4 lesson).
static __device__ __forceinline__ unsigned umed3(unsigned a, unsigned b, unsigned c) {
    unsigned d;
    asm("v_med3_u32 %0, %1, %2, %3" : "=v"(d) : "v"(a), "v"(b), "v"(c));
    return d;
}

// ---------------- prologue 1: split NEGATED codebook into bf16 hi/lo granules ----------------
// ws_cb layout: [q][ch16][plane16][code64], plane = term*8 + kt*4 + g. Stores -c.
__global__ __launch_bounds__(256) void prep_cb(const float* __restrict__ cb,
                                               int4* __restrict__ ws_cb) {
    int id = blockIdx.x * 256 + threadIdx.x;       // 0 .. 131071
    int n_rel = id & 63;
    int plane = (id >> 6) & 15;
    int ch    = (id >> 10) & 15;
    int q     = id >> 14;
    int g = plane & 3, kt = (plane >> 2) & 1, term = plane >> 3;
    int n = ch * CHUNK + n_rel;
    const float* src = cb + ((size_t)(q * KCODES + n)) * D + kt * 32 + g * 8;
    union { short s[8]; int4 v; } u;
    #pragma unroll
    for (int j = 0; j < 8; ++j) {
        float f = -src[j];                         // NEGATED
        unsigned hb = bf16_rne_bits(f);
        if (term == 0) {
            u.s[j] = (short)hb;
        } else {
            float lo = f - __uint_as_float(hb << 16);
            u.s[j] = (short)bf16_rne_bits(lo);
        }
    }
    ws_cb[id] = u.v;
}

// ---------------- prologue 2: c_sq exact (refine) + seed (csq/2 + BIAS, approx) ----------------
__global__ __launch_bounds__(256) void prep_csq(const float* __restrict__ cb,
                                                float* __restrict__ ws_csq,
                                                float* __restrict__ ws_csqh) {
    int id = blockIdx.x * 256 + threadIdx.x;       // 0 .. 8191
    const float* c = cb + (size_t)id * D;
    float s0 = 0.f, s1 = 0.f, s2 = 0.f, s3 = 0.f;
    #pragma unroll
    for (int j = 0; j < 16; ++j) {
        s0 = fmaf(c[4*j+0], c[4*j+0], s0);
        s1 = fmaf(c[4*j+1], c[4*j+1], s1);
        s2 = fmaf(c[4*j+2], c[4*j+2], s2);
        s3 = fmaf(c[4*j+3], c[4*j+3], s3);
    }
    float cs = (s0 + s1) + (s2 + s3);
    ws_csq[id]  = cs;                // exact, refine comparator (bit-identical to prior rounds)
    ws_csqh[id] = 0.5f * cs + BIAS;  // approx seed: acc = seed - dot (always > 0)
}

// ---------------- main kernel ----------------
// R6: occupancy experiment. TOKPB 64 -> 32 (grid 2048 -> 8 blocks/CU, 32 waves/CU).
// Wave (group, half) = 16 tokens x 16 codes of each 32-code chunk (s-loop removed).
// Direct global->VGPR B loads, NO software prefetch: latency hidden by TLP (8 waves/SIMD).
// Candidate enumeration, comparator arithmetic, merges, refine: index-identical to R2/R5.
__global__ __launch_bounds__(TPB, 8) void rvq_mfma(
    const float* __restrict__ x,
    const float* __restrict__ cb,
    const int4* __restrict__ ws_cb,
    const float* __restrict__ ws_csq,
    float* __restrict__ out)
{
    __shared__ __align__(16) float lds_resid[TOKPB * 68];  // 8704 B persistent residual
    __shared__ __align__(16) float lds_csqh_q[KCODES];     // 4 KB: this q's seed row
    __shared__ unsigned lds_cand[2][TOKPB * 3];            // 768 B packed top-3 per half
    __shared__ int      lds_pick[TOKPB];                   // 128 B

    const int tid   = threadIdx.x;
    const int lane  = tid & 63;
    const int wave  = tid >> 6;          // 0..3
    const int group = wave >> 1;         // 0..1 (token group of 16)
    const int half  = wave & 1;          // code half (16 codes of the 32-chunk)
    const int g     = lane >> 4;         // quad
    const int c     = lane & 15;
    const int tok0  = blockIdx.x * TOKPB;
    const float* ws_csqh = ws_csq + 8192;

    // ---- init: residual = x, into LDS (8 threads per token, 8 floats each) ----
    {
        const int t = tid >> 3, part = tid & 7;
        const float4* xp = (const float4*)(x + (size_t)(tok0 + t) * D + part * 8);
        float4* rr = (float4*)(lds_resid + t * 68 + part * 8);
        rr[0] = xp[0];
        rr[1] = xp[1];
    }

    // per-lane constant: int4 offset of this lane's B-fragment within a chunk's span.
    // frag at ws_cb[base(q,ch) + g*64 + half*16 + c]; +256 hi-kt1; +512 lo-kt0; +768 lo-kt1.
    const int lid = (g << 6) + (half << 4) + c;
    const int sdo = (half << 4) + c;     // csqh/codev low bits

    for (int q = 0; q < NQ; ++q) {
        // ---- stage this q's 1024 seeds into LDS (4 floats per thread) ----
        {
            const float4 v = *(const float4*)(ws_csqh + (q << 10) + (tid << 2));
            *(float4*)(lds_csqh_q + (tid << 2)) = v;
        }
        __syncthreads();   // residual/csqh visible; prev q fully retired

        // ---- A-split for the group's 16-token sub-tile ----
        short8 ah0, ah1, al0, al1;
        {
            const float* rr = lds_resid + (group * 16 + c) * 68;
            float4 f0 = *(const float4*)(rr + 8 * g);
            float4 f1 = *(const float4*)(rr + 8 * g + 4);
            float4 f2 = *(const float4*)(rr + 32 + 8 * g);
            float4 f3 = *(const float4*)(rr + 36 + 8 * g);
            const float* v0 = (const float*)&f0;
            const float* v1 = (const float*)&f1;
            const float* v2 = (const float*)&f2;
            const float* v3 = (const float*)&f3;
            #pragma unroll
            for (int j = 0; j < 4; ++j) {
                float a = v0[j], b = v1[j], e = v2[j], f = v3[j];
                unsigned ha = bf16_rne_bits(a);
                unsigned hb = bf16_rne_bits(b);
                unsigned he = bf16_rne_bits(e);
                unsigned hf = bf16_rne_bits(f);
                ah0[j]   = (short)ha;  ah0[4+j] = (short)hb;
                ah1[j]   = (short)he;  ah1[4+j] = (short)hf;
                al0[j]   = (short)bf16_rne_bits(a - __uint_as_float(ha << 16));
                al0[4+j] = (short)bf16_rne_bits(b - __uint_as_float(hb << 16));
                al1[j]   = (short)bf16_rne_bits(e - __uint_as_float(he << 16));
                al1[4+j] = (short)bf16_rne_bits(f - __uint_as_float(hf << 16));
            }
        }

        // packed top-3 per row — ascending u32
        unsigned T1[4], T2[4], T3[4];
        #pragma unroll
        for (int r = 0; r < 4; ++r) { T1[r] = 0xFFFFFFFFu; T2[r] = 0xFFFFFFFFu; T3[r] = 0xFFFFFFFFu; }

        // ---- barrier-free chunk loop over 32 x 32-code chunks; TLP hides L2 latency ----
        const int4* fpq = ws_cb + ((size_t)q << 14) + lid;    // base(q, ch=0) + lane offset
        #pragma unroll 1
        for (int ch = 0; ch < 32; ++ch) {
            const int4* fp = fpq + ((ch >> 1) << 10) + ((ch & 1) << 5);
            const short8 bh0 = *(const short8*)(fp);
            const short8 bh1 = *(const short8*)(fp + 256);
            const short8 bl0 = *(const short8*)(fp + 512);
            const short8 bl1 = *(const short8*)(fp + 768);
            const int cv = (ch << 5) + sdo;
            const float sd = lds_csqh_q[cv];
            const unsigned codev = (unsigned)cv;
            f32x4 acc = {sd, sd, sd, sd};
            acc = __builtin_amdgcn_mfma_f32_16x16x32_bf16(ah0, bh0, acc, 0, 0, 0);
            acc = __builtin_amdgcn_mfma_f32_16x16x32_bf16(ah1, bh1, acc, 0, 0, 0);
            acc = __builtin_amdgcn_mfma_f32_16x16x32_bf16(al0, bh0, acc, 0, 0, 0);
            acc = __builtin_amdgcn_mfma_f32_16x16x32_bf16(ah0, bl0, acc, 0, 0, 0);
            acc = __builtin_amdgcn_mfma_f32_16x16x32_bf16(al1, bh1, acc, 0, 0, 0);
            acc = __builtin_amdgcn_mfma_f32_16x16x32_bf16(ah1, bl1, acc, 0, 0, 0);
            #pragma unroll
            for (int r = 0; r < 4; ++r) {
                const unsigned p = (__float_as_uint(acc[r]) & 0xFFFFFC00u) | codev;
                const unsigned t1o = T1[r], t2o = T2[r];
                T1[r] = umn(t1o, p);             // given t1o<=t2o<=T3: bit-identical
                T2[r] = umed3(t1o, t2o, p);      //   to min(T2,max(T1,p))
                T3[r] = umed3(t2o, T3[r], p);    //   and min(T3,max(T2,p))
            }
        }

        // ---- cross-lane top-3 merge over the 16 c-lanes ----
        #pragma unroll
        for (int st = 1; st <= 8; st <<= 1) {
            #pragma unroll
            for (int r = 0; r < 4; ++r) {
                unsigned o1 = (unsigned)__shfl_xor((int)T1[r], st);
                unsigned o2 = (unsigned)__shfl_xor((int)T2[r], st);
                unsigned o3 = (unsigned)__shfl_xor((int)T3[r], st);
                unsigned x1 = umn(T1[r], o1), y1 = umx(T1[r], o1);
                unsigned x2 = umn(T2[r], o2), y2 = umx(T2[r], o2);
                unsigned x3 = umn(T3[r], o3);
                T1[r] = x1;
                T3[r] = umed3(y1, x2, umn(y2, x3));
                T2[r] = umn(y1, x2);
            }
        }

        // ---- publish per-half candidates ----
        if (c == 0) {
            #pragma unroll
            for (int r = 0; r < 4; ++r) {
                const int idx = (group * 16 + g * 4 + r) * 3;
                lds_cand[half][idx + 0] = T1[r];
                lds_cand[half][idx + 1] = T2[r];
                lds_cand[half][idx + 2] = T3[r];
            }
        }
        __syncthreads();

        // ---- cross-half merge + ALWAYS-ON exact refinement ----
        // waves 0,2 cover rows 0..15; waves 1,3 cover rows 16..31 (duplicates benign:
        // identical inputs -> identical pick -> same-value write).
        {
            const int t4  = lane >> 2;          // token within 16-row slab
            const int sel = lane & 3;           // candidate slot (3 duplicates slot 2)
            const int row = half * 16 + t4;
            unsigned a1 = lds_cand[0][row * 3 + 0];
            unsigned a2 = lds_cand[0][row * 3 + 1];
            unsigned a3 = lds_cand[0][row * 3 + 2];
            unsigned b1 = lds_cand[1][row * 3 + 0];
            unsigned b2 = lds_cand[1][row * 3 + 1];
            unsigned b3 = lds_cand[1][row * 3 + 2];
            unsigned x1 = umn(a1, b1), y1 = umx(a1, b1);
            unsigned x2 = umn(a2, b2), y2 = umx(a2, b2);
            unsigned x3 = umn(a3, b3);
            unsigned m1 = x1;
            unsigned m2 = umn(y1, x2);
            unsigned m3 = umed3(y1, x2, umn(y2, x3));
            const unsigned psel = (sel == 0) ? m1 : ((sel == 1) ? m2 : m3);
            const int cd = (int)(psel & 1023u);

            // exact fp32 distance, bit-identical comparator arithmetic to prior rounds
            const float4* rrv = (const float4*)(lds_resid + row * 68);
            const float4* cpv = (const float4*)(cb + ((size_t)(q * KCODES + cd)) * D);
            float ax = 0.f, ay = 0.f, az = 0.f, aw = 0.f;
            #pragma unroll
            for (int j = 0; j < 16; ++j) {
                float4 rv = rrv[j];
                float4 cv = cpv[j];
                ax = fmaf(rv.x, cv.x, ax);
                ay = fmaf(rv.y, cv.y, ay);
                az = fmaf(rv.z, cv.z, az);
                aw = fmaf(rv.w, cv.w, aw);
            }
            float dot = (ax + ay) + (az + aw);
            float dd = fmaf(dot, -2.0f, ws_csq[q * KCODES + cd]);

            const int base = lane & ~3;
            float d0 = __shfl(dd, base);
            float d1 = __shfl(dd, base + 1);
            float d2 = __shfl(dd, base + 2);
            int cc0 = (int)(m1 & 1023u);
            int cc1 = (int)(m2 & 1023u);
            int cc2 = (int)(m3 & 1023u);
            float db = d0; int pick = cc0;
            if (d1 < db || (d1 == db && cc1 < pick)) { db = d1; pick = cc1; }
            if (d2 < db || (d2 == db && cc2 < pick)) { db = d2; pick = cc2; }
            if (sel == 0) lds_pick[row] = pick;
        }
        __syncthreads();

        // ---- residual update in LDS: resid -= cb[q][ifin] (8 threads per token) ----
        {
            const int t = tid >> 3, part = tid & 7;
            const int ifin = lds_pick[t];
            const float4* cp = (const float4*)(cb + ((size_t)(q * KCODES + ifin)) * D + part * 8);
            float4* rr = (float4*)(lds_resid + t * 68 + part * 8);
            #pragma unroll
            for (int k2 = 0; k2 < 2; ++k2) {
                float4 rv = rr[k2], cv = cp[k2];
                rv.x -= cv.x; rv.y -= cv.y; rv.z -= cv.z; rv.w -= cv.w;
                rr[k2] = rv;
            }
        }
    }

    // ---- epilogue: out = x - residual_final (8 threads per token) ----
    __syncthreads();
    {
        const int t = tid >> 3, part = tid & 7;
        const float4* xp = (const float4*)(x + (size_t)(tok0 + t) * D + part * 8);
        const float4* rr = (const float4*)(lds_resid + t * 68 + part * 8);
        float4* op = (float4*)(out + (size_t)(tok0 + t) * D + part * 8);
        #pragma unroll
        for (int k2 = 0; k2 < 2; ++k2) {
            float4 xv = xp[k2], rv = rr[k2];
            float4 o;
            o.x = xv.x - rv.x; o.y = xv.y - rv.y;
            o.z = xv.z - rv.z; o.w = xv.w - rv.w;
            op[k2] = o;
        }
    }
}

extern "C" void kernel_launch(void* const* d_in, const int* in_sizes, int n_in,
                              void* d_out, int out_size, void* d_ws, size_t ws_size,
                              hipStream_t stream) {
    const float* x  = (const float*)d_in[0];
    const float* cb = (const float*)d_in[1];
    float* out = (float*)d_out;

    int4*  ws_cb   = (int4*)d_ws;                                      // 2 MB
    float* ws_csq  = (float*)((char*)d_ws + (size_t)2 * 1024 * 1024);  // 32 KB exact
    float* ws_csqh = ws_csq + 8192;                                    // 32 KB seed (= ws_csq+8192)

    prep_cb <<<512, 256, 0, stream>>>(cb, ws_cb);
    prep_csq<<< 32, 256, 0, stream>>>(cb, ws_csq, ws_csqh);

    const int n_tokens = in_sizes[0] / D;            // 65536
    const int grid = n_tokens / TOKPB;               // 2048 blocks
    rvq_mfma<<<grid, TPB, 0, stream>>>(x, cb, ws_cb, ws_csq, out);
}

// Round 7
// 334.324 us; speedup vs baseline: 1.4215x; 1.4215x over previous
//
#include <hip/hip_runtime.h>

#define NQ 8
#define KCODES 1024
#define D 64
#define CHUNK 64             // prep_cb granule (64-code chunks, ws_cb layout unchanged)
#define TPB 256
#define TOKPB 64             // tokens per block = 2 groups x 32
#define BIAS 96.0f

using short8 = __attribute__((ext_vector_type(8))) short;
using f32x4  = __attribute__((ext_vector_type(4))) float;

static __device__ __forceinline__ unsigned bf16_rne_bits(float f) {
    unsigned u = __float_as_uint(f);
    return (u + 0x7fffu + ((u >> 16) & 1u)) >> 16;   // bf16 RNE bit pattern
}
static __device__ __forceinline__ unsigned umn(unsigned a, unsigned b) { return a < b ? a : b; }
static __device__ __forceinline__ unsigned umx(unsigned a, unsigned b) { return a > b ? a : b; }
// true 3-input median in one VOP3 (no clang builtin for u32 med3 -> inline asm).
// NOTE: inputs must NOT be direct MFMA outputs (hazard cover) — keep >=1 plain VALU op
// between an MFMA result and any inline-asm consumer (R3/R4 lesson: v_and_or_b32
// reading acc[] directly was the correctness bug).
static __device__ __forceinline__ unsigned umed3(unsigned a, unsigned b, unsigned c) {
    unsigned d;
    asm("v_med3_u32 %0, %1, %2, %3" : "=v"(d) : "v"(a), "v"(b), "v"(c));
    return d;
}

// ---------------- prologue 1: split NEGATED codebook into bf16 hi/lo granules ----------------
// ws_cb layout: [q][ch16][plane16][code64], plane = term*8 + kt*4 + g. Stores -c.
__global__ __launch_bounds__(256) void prep_cb(const float* __restrict__ cb,
                                               int4* __restrict__ ws_cb) {
    int id = blockIdx.x * 256 + threadIdx.x;       // 0 .. 131071
    int n_rel = id & 63;
    int plane = (id >> 6) & 15;
    int ch    = (id >> 10) & 15;
    int q     = id >> 14;
    int g = plane & 3, kt = (plane >> 2) & 1, term = plane >> 3;
    int n = ch * CHUNK + n_rel;
    const float* src = cb + ((size_t)(q * KCODES + n)) * D + kt * 32 + g * 8;
    union { short s[8]; int4 v; } u;
    #pragma unroll
    for (int j = 0; j < 8; ++j) {
        float f = -src[j];                         // NEGATED
        unsigned hb = bf16_rne_bits(f);
        if (term == 0) {
            u.s[j] = (short)hb;
        } else {
            float lo = f - __uint_as_float(hb << 16);
            u.s[j] = (short)bf16_rne_bits(lo);
        }
    }
    ws_cb[id] = u.v;
}

// ---------------- prologue 2: c_sq exact (refine) + seed (csq/2 + BIAS, approx) ----------------
__global__ __launch_bounds__(256) void prep_csq(const float* __restrict__ cb,
                                                float* __restrict__ ws_csq,
                                                float* __restrict__ ws_csqh) {
    int id = blockIdx.x * 256 + threadIdx.x;       // 0 .. 8191
    const float* c = cb + (size_t)id * D;
    float s0 = 0.f, s1 = 0.f, s2 = 0.f, s3 = 0.f;
    #pragma unroll
    for (int j = 0; j < 16; ++j) {
        s0 = fmaf(c[4*j+0], c[4*j+0], s0);
        s1 = fmaf(c[4*j+1], c[4*j+1], s1);
        s2 = fmaf(c[4*j+2], c[4*j+2], s2);
        s3 = fmaf(c[4*j+3], c[4*j+3], s3);
    }
    float cs = (s0 + s1) + (s2 + s3);
    ws_csq[id]  = cs;                // exact, refine comparator (bit-identical to prior rounds)
    ws_csqh[id] = 0.5f * cs + BIAS;  // approx seed: acc = seed - dot (always > 0)
}

// ---- issue chunk CH's B-fragments + seed into SSA register set S (no rotation movs) ----
#define ISSUE(S, CH) do {                                                                 \
    const int4* fp_ = fpq + (((CH) >> 1) << 10) + (((CH) & 1) << 5);                      \
    S##f0 = *(const short8*)(fp_);                                                        \
    S##f1 = *(const short8*)(fp_ + 256);                                                  \
    S##f2 = *(const short8*)(fp_ + 512);                                                  \
    S##f3 = *(const short8*)(fp_ + 768);                                                  \
    S##sd = sdq[(CH) << 5];                                                               \
} while (0)

// ---- 12 MFMA + pack + top-3 insert for chunk CH from set S (arithmetic verbatim R2) ----
#define COMPUTE(S, CH) do {                                                               \
    const unsigned codev_ = (unsigned)(((CH) << 5) + sdo);                                \
    const float sd_ = S##sd;                                                              \
    _Pragma("unroll")                                                                     \
    for (int s = 0; s < 2; ++s) {                                                         \
        f32x4 acc = {sd_, sd_, sd_, sd_};                                                 \
        acc = __builtin_amdgcn_mfma_f32_16x16x32_bf16(ah0[s], S##f0, acc, 0, 0, 0);       \
        acc = __builtin_amdgcn_mfma_f32_16x16x32_bf16(ah1[s], S##f1, acc, 0, 0, 0);       \
        acc = __builtin_amdgcn_mfma_f32_16x16x32_bf16(al0[s], S##f0, acc, 0, 0, 0);       \
        acc = __builtin_amdgcn_mfma_f32_16x16x32_bf16(ah0[s], S##f2, acc, 0, 0, 0);       \
        acc = __builtin_amdgcn_mfma_f32_16x16x32_bf16(al1[s], S##f1, acc, 0, 0, 0);       \
        acc = __builtin_amdgcn_mfma_f32_16x16x32_bf16(ah1[s], S##f3, acc, 0, 0, 0);       \
        _Pragma("unroll")                                                                 \
        for (int r = 0; r < 4; ++r) {                                                     \
            const unsigned p = (__float_as_uint(acc[r]) & 0xFFFFFC00u) | codev_;          \
            const unsigned t1o = T1[s][r], t2o = T2[s][r];                                \
            T1[s][r] = umn(t1o, p);             /* given t1o<=t2o<=T3: bit-identical */   \
            T2[s][r] = umed3(t1o, t2o, p);      /*   to min(T2,max(T1,p))            */   \
            T3[s][r] = umed3(t2o, T3[s][r], p); /*   and min(T3,max(T2,p))           */   \
        }                                                                                 \
    }                                                                                     \
} while (0)

// ---------------- main kernel ----------------
// Wave (group, half) = 32 tokens x 16 codes of each 32-code chunk. 4 blocks/CU.
// Barrier-free chunk loop; B-fragments + seed direct global->VGPR (L2-resident).
// R7: 3-set SSA software pipeline, depth-2 cover (each chunk's loads issued two full
// COMPUTE phases before use; prologue covered by the A-split). No rotation movs.
__global__ __launch_bounds__(TPB, 4) void rvq_mfma(
    const float* __restrict__ x,
    const float* __restrict__ cb,
    const int4* __restrict__ ws_cb,
    const float* __restrict__ ws_csq,
    float* __restrict__ out)
{
    __shared__ __align__(16) float lds_resid[TOKPB * 68];  // 17408 B persistent residual
    __shared__ unsigned lds_cand[2][TOKPB * 3];            // 1536 B packed top-3 per half
    __shared__ int      lds_pick[TOKPB];                   // 256 B

    const int tid   = threadIdx.x;
    const int lane  = tid & 63;
    const int wave  = tid >> 6;          // 0..3
    const int group = wave >> 1;         // 0..1 (token group of 32)
    const int half  = wave & 1;          // code half (16 codes of the 32-chunk)
    const int g     = lane >> 4;         // quad
    const int c     = lane & 15;
    const int tok0  = blockIdx.x * TOKPB;
    const float* ws_csqh = ws_csq + 8192;

    // ---- init: residual = x, into LDS (4 threads per token) ----
    {
        const int t = tid >> 2, part = tid & 3;
        const float4* xp = (const float4*)(x + (size_t)(tok0 + t) * D + part * 16);
        float4* rr = (float4*)(lds_resid + t * 68 + part * 16);
        #pragma unroll
        for (int k2 = 0; k2 < 4; ++k2) rr[k2] = xp[k2];
    }

    // per-lane constant: int4 offset of this lane's B-fragment within a chunk's span.
    // frag at ws_cb[base(q,ch) + g*64 + half*16 + c]; +256 hi-kt1; +512 lo-kt0; +768 lo-kt1.
    const int lid = (g << 6) + (half << 4) + c;
    const int sdo = (half << 4) + c;     // csqh/codev low bits

    // three B-fragment register sets (SSA, macro-addressed)
    short8 P0f0, P0f1, P0f2, P0f3;  float P0sd;
    short8 P1f0, P1f1, P1f2, P1f3;  float P1sd;
    short8 P2f0, P2f1, P2f2, P2f3;  float P2sd;

    for (int q = 0; q < NQ; ++q) {
        __syncthreads();   // residual state visible (init or previous q's update)

        const int4*  fpq = ws_cb + ((size_t)q << 14) + lid;   // base(q, ch=0) + lane offset
        const float* sdq = ws_csqh + (q << 10) + sdo;

        // prologue: first two chunks in flight; latency covered by the A-split below
        ISSUE(P0, 0);
        ISSUE(P1, 1);

        // ---- A-split for the group's two 16-token sub-tiles ----
        short8 ah0[2], ah1[2], al0[2], al1[2];
        #pragma unroll
        for (int s = 0; s < 2; ++s) {
            const float* rr = lds_resid + (group * 32 + s * 16 + c) * 68;
            float4 f0 = *(const float4*)(rr + 8 * g);
            float4 f1 = *(const float4*)(rr + 8 * g + 4);
            float4 f2 = *(const float4*)(rr + 32 + 8 * g);
            float4 f3 = *(const float4*)(rr + 36 + 8 * g);
            const float* v0 = (const float*)&f0;
            const float* v1 = (const float*)&f1;
            const float* v2 = (const float*)&f2;
            const float* v3 = (const float*)&f3;
            #pragma unroll
            for (int j = 0; j < 4; ++j) {
                float a = v0[j], b = v1[j], e = v2[j], f = v3[j];
                unsigned ha = bf16_rne_bits(a);
                unsigned hb = bf16_rne_bits(b);
                unsigned he = bf16_rne_bits(e);
                unsigned hf = bf16_rne_bits(f);
                ah0[s][j]   = (short)ha;  ah0[s][4+j] = (short)hb;
                ah1[s][j]   = (short)he;  ah1[s][4+j] = (short)hf;
                al0[s][j]   = (short)bf16_rne_bits(a - __uint_as_float(ha << 16));
                al0[s][4+j] = (short)bf16_rne_bits(b - __uint_as_float(hb << 16));
                al1[s][j]   = (short)bf16_rne_bits(e - __uint_as_float(he << 16));
                al1[s][4+j] = (short)bf16_rne_bits(f - __uint_as_float(hf << 16));
            }
        }

        // packed top-3 per (sub-tile, row) — ascending u32
        unsigned T1[2][4], T2[2][4], T3[2][4];
        #pragma unroll
        for (int s = 0; s < 2; ++s)
            #pragma unroll
            for (int r = 0; r < 4; ++r) { T1[s][r] = 0xFFFFFFFFu; T2[s][r] = 0xFFFFFFFFu; T3[s][r] = 0xFFFFFFFFu; }

        // ---- barrier-free pipelined chunk loop: 3 sets, depth-2 cover, no rotation ----
        #pragma unroll 1
        for (int cp = 0; cp < 10; ++cp) {
            const int ch = cp * 3;
            ISSUE(P2, ch + 2); COMPUTE(P0, ch);
            ISSUE(P0, ch + 3); COMPUTE(P1, ch + 1);
            ISSUE(P1, ch + 4); COMPUTE(P2, ch + 2);
        }
        COMPUTE(P0, 30);
        COMPUTE(P1, 31);

        // ---- cross-lane top-3 merge over the 16 c-lanes ----
        #pragma unroll
        for (int st = 1; st <= 8; st <<= 1) {
            #pragma unroll
            for (int s = 0; s < 2; ++s) {
                #pragma unroll
                for (int r = 0; r < 4; ++r) {
                    unsigned o1 = (unsigned)__shfl_xor((int)T1[s][r], st);
                    unsigned o2 = (unsigned)__shfl_xor((int)T2[s][r], st);
                    unsigned o3 = (unsigned)__shfl_xor((int)T3[s][r], st);
                    unsigned x1 = umn(T1[s][r], o1), y1 = umx(T1[s][r], o1);
                    unsigned x2 = umn(T2[s][r], o2), y2 = umx(T2[s][r], o2);
                    unsigned x3 = umn(T3[s][r], o3);
                    T1[s][r] = x1;
                    T3[s][r] = umed3(y1, x2, umn(y2, x3));
                    T2[s][r] = umn(y1, x2);
                }
            }
        }

        // ---- publish per-half candidates ----
        if (c == 0) {
            #pragma unroll
            for (int s = 0; s < 2; ++s)
                #pragma unroll
                for (int r = 0; r < 4; ++r) {
                    const int idx = (group * 32 + s * 16 + g * 4 + r) * 3;
                    lds_cand[half][idx + 0] = T1[s][r];
                    lds_cand[half][idx + 1] = T2[s][r];
                    lds_cand[half][idx + 2] = T3[s][r];
                }
        }
        __syncthreads();

        // ---- cross-half merge + ALWAYS-ON exact refinement (each wave: 16 tokens) ----
        {
            const int t4  = lane >> 2;          // token within sub-tile
            const int sel = lane & 3;           // candidate slot (3 duplicates slot 2)
            const int row = group * 32 + half * 16 + t4;
            unsigned a1 = lds_cand[0][row * 3 + 0];
            unsigned a2 = lds_cand[0][row * 3 + 1];
            unsigned a3 = lds_cand[0][row * 3 + 2];
            unsigned b1 = lds_cand[1][row * 3 + 0];
            unsigned b2 = lds_cand[1][row * 3 + 1];
            unsigned b3 = lds_cand[1][row * 3 + 2];
            unsigned x1 = umn(a1, b1), y1 = umx(a1, b1);
            unsigned x2 = umn(a2, b2), y2 = umx(a2, b2);
            unsigned x3 = umn(a3, b3);
            unsigned m1 = x1;
            unsigned m2 = umn(y1, x2);
            unsigned m3 = umed3(y1, x2, umn(y2, x3));
            const unsigned psel = (sel == 0) ? m1 : ((sel == 1) ? m2 : m3);
            const int cd = (int)(psel & 1023u);

            // exact fp32 distance, bit-identical comparator arithmetic to prior rounds
            const float4* rrv = (const float4*)(lds_resid + row * 68);
            const float4* cpv = (const float4*)(cb + ((size_t)(q * KCODES + cd)) * D);
            float ax = 0.f, ay = 0.f, az = 0.f, aw = 0.f;
            #pragma unroll
            for (int j = 0; j < 16; ++j) {
                float4 rv = rrv[j];
                float4 cv = cpv[j];
                ax = fmaf(rv.x, cv.x, ax);
                ay = fmaf(rv.y, cv.y, ay);
                az = fmaf(rv.z, cv.z, az);
                aw = fmaf(rv.w, cv.w, aw);
            }
            float dot = (ax + ay) + (az + aw);
            float dd = fmaf(dot, -2.0f, ws_csq[q * KCODES + cd]);

            const int base = lane & ~3;
            float d0 = __shfl(dd, base);
            float d1 = __shfl(dd, base + 1);
            float d2 = __shfl(dd, base + 2);
            int cc0 = (int)(m1 & 1023u);
            int cc1 = (int)(m2 & 1023u);
            int cc2 = (int)(m3 & 1023u);
            float db = d0; int pick = cc0;
            if (d1 < db || (d1 == db && cc1 < pick)) { db = d1; pick = cc1; }
            if (d2 < db || (d2 == db && cc2 < pick)) { db = d2; pick = cc2; }
            if (sel == 0) lds_pick[row] = pick;
        }
        __syncthreads();

        // ---- residual update in LDS: resid -= cb[q][ifin] (4 threads per token) ----
        {
            const int t = tid >> 2, part = tid & 3;
            const int ifin = lds_pick[t];
            const float4* cp = (const float4*)(cb + ((size_t)(q * KCODES + ifin)) * D + part * 16);
            float4* rr = (float4*)(lds_resid + t * 68 + part * 16);
            #pragma unroll
            for (int k2 = 0; k2 < 4; ++k2) {
                float4 rv = rr[k2], cv = cp[k2];
                rv.x -= cv.x; rv.y -= cv.y; rv.z -= cv.z; rv.w -= cv.w;
                rr[k2] = rv;
            }
        }
    }

    // ---- epilogue: out = x - residual_final (4 threads per token) ----
    __syncthreads();
    {
        const int t = tid >> 2, part = tid & 3;
        const float4* xp = (const float4*)(x + (size_t)(tok0 + t) * D + part * 16);
        const float4* rr = (const float4*)(lds_resid + t * 68 + part * 16);
        float4* op = (float4*)(out + (size_t)(tok0 + t) * D + part * 16);
        #pragma unroll
        for (int k2 = 0; k2 < 4; ++k2) {
            float4 xv = xp[k2], rv = rr[k2];
            float4 o;
            o.x = xv.x - rv.x; o.y = xv.y - rv.y;
            o.z = xv.z - rv.z; o.w = xv.w - rv.w;
            op[k2] = o;
        }
    }
}

extern "C" void kernel_launch(void* const* d_in, const int* in_sizes, int n_in,
                              void* d_out, int out_size, void* d_ws, size_t ws_size,
                              hipStream_t stream) {
    const float* x  = (const float*)d_in[0];
    const float* cb = (const float*)d_in[1];
    float* out = (float*)d_out;

    int4*  ws_cb   = (int4*)d_ws;                                      // 2 MB
    float* ws_csq  = (float*)((char*)d_ws + (size_t)2 * 1024 * 1024);  // 32 KB exact
    float* ws_csqh = ws_csq + 8192;                                    // 32 KB seed (= ws_csq+8192)

    prep_cb <<<512, 256, 0, stream>>>(cb, ws_cb);
    prep_csq<<< 32, 256, 0, stream>>>(cb, ws_csq, ws_csqh);

    const int n_tokens = in_sizes[0] / D;            // 65536
    const int grid = n_tokens / TOKPB;               // 1024 blocks
    rvq_mfma<<<grid, TPB, 0, stream>>>(x, cb, ws_cb, ws_csq, out);
}